// Round 8
// baseline (1878.690 us; speedup 1.0000x reference)
//
#include <hip/hip_runtime.h>

#define T_TOK 8192   // B*S tokens
#define HDIM  2048
#define IDIM  8192
#define KKEEP 4096

typedef _Float16 f16x8 __attribute__((ext_vector_type(8)));
typedef float    f32x4 __attribute__((ext_vector_type(4)));

#define AS1 __attribute__((address_space(1)))
#define AS3 __attribute__((address_space(3)))

// LDS swizzle within a 16KB half-tile (128 rows x 128B): byte ^= (row&7)<<4.
__device__ __forceinline__ int swz(int b) { return b ^ (((b >> 7) & 7) << 4); }

#define BARR asm volatile("s_barrier" ::: "memory")
// barrier -> drain own ds_reads -> pin (rule #18) ; MFMA follows
#define SYNC_MFMA do { BARR; \
    asm volatile("s_waitcnt lgkmcnt(0)" ::: "memory"); \
    __builtin_amdgcn_sched_barrier(0); } while (0)

// ---------------- cast kernels ----------------

__global__ void cast_split(const float4* __restrict__ in, ushort4* __restrict__ hi,
                           ushort4* __restrict__ lo2, long n4) {
    long stride = (long)gridDim.x * blockDim.x;
    for (long i = (long)blockIdx.x * blockDim.x + threadIdx.x; i < n4; i += stride) {
        float4 v = in[i];
        float vv[4] = {v.x, v.y, v.z, v.w};
        union { _Float16 f[4]; ushort4 u; } H, L;
        #pragma unroll
        for (int j = 0; j < 4; ++j) {
            _Float16 h = (_Float16)vv[j];
            H.f[j] = h;
            L.f[j] = (_Float16)((vv[j] - (float)h) * 2048.0f);
        }
        hi[i] = H.u;
        lo2[i] = L.u;
    }
}

__global__ void cast_f16(const float4* __restrict__ in, ushort4* __restrict__ o, long n4) {
    long stride = (long)gridDim.x * blockDim.x;
    for (long i = (long)blockIdx.x * blockDim.x + threadIdx.x; i < n4; i += stride) {
        float4 v = in[i];
        float vv[4] = {v.x, v.y, v.z, v.w};
        union { _Float16 f[4]; ushort4 u; } H;
        #pragma unroll
        for (int j = 0; j < 4; ++j) H.f[j] = (_Float16)vv[j];
        o[i] = H.u;
    }
}

// ---------------- 256x256 GEMM, template-faithful 4-phase K-tile ----------------
// MODE 0: DOWN — Cf = A0@B0^T (f32)
// MODE 1: UP   — in-place GP[idx] = (f16)((float)GP[idx] * acc)
// MODE 2: GATE — acc = A0@B0^T + A1@B1^T; acc *= 2^-11; acc += A2@B2^T; Cf f32

#define RD_A(dst_, mh_, buf_) do { \
    const char* b_ = Lc + (buf_)*65536 + (mh_)*16384; \
    _Pragma("unroll") \
    for (int f_ = 0; f_ < 4; ++f_) { \
      (dst_)[f_][0] = *(const f16x8*)(b_ + aof0 + f_*2048); \
      (dst_)[f_][1] = *(const f16x8*)(b_ + aof1 + f_*2048); \
    } \
  } while (0)

#define RD_B(dst_, nh_, buf_) do { \
    const char* b_ = Lc + (buf_)*65536 + 32768 + (nh_)*16384; \
    _Pragma("unroll") \
    for (int n_ = 0; n_ < 2; ++n_) { \
      (dst_)[n_][0] = *(const f16x8*)(b_ + bof0 + n_*2048); \
      (dst_)[n_][1] = *(const f16x8*)(b_ + bof1 + n_*2048); \
    } \
  } while (0)

#define QUADM(af_, bf_, mh_, nh_) do { \
    __builtin_amdgcn_s_setprio(1); \
    _Pragma("unroll") \
    for (int f_ = 0; f_ < 4; ++f_) { \
      _Pragma("unroll") \
      for (int n_ = 0; n_ < 2; ++n_) { \
        _Pragma("unroll") \
        for (int k_ = 0; k_ < 2; ++k_) \
          acc[(mh_)*4+f_][(nh_)*2+n_] = __builtin_amdgcn_mfma_f32_16x16x32_f16( \
              (af_)[f_][k_], (bf_)[n_][k_], acc[(mh_)*4+f_][(nh_)*2+n_], 0, 0, 0); \
      } \
    } \
    __builtin_amdgcn_s_setprio(0); \
  } while (0)

// stage one half-tile: mat_ 0=A 1=B, h_ half, buf_ target buffer
#define STAGE(ok_, pA_, pB_, kt_, mat_, h_, buf_) do { \
    if (ok_) { \
      const _Float16* mb_ = (mat_) == 0 ? (pA_) : (pB_); \
      const int rb_ = ((mat_) == 0 ? bm : bn) * 256 + (h_)*128; \
      char* ld_ = ldsw + (buf_)*65536 + (mat_)*32768 + (h_)*16384; \
      __builtin_amdgcn_global_load_lds((const AS1 void*)(mb_ + (size_t)(rb_ + srow0)*Kp + (kt_) + scol0), \
                                       (AS3 void*)ld_, 16, 0, 0); \
      __builtin_amdgcn_global_load_lds((const AS1 void*)(mb_ + (size_t)(rb_ + srow1)*Kp + (kt_) + scol1), \
                                       (AS3 void*)(ld_ + 8192), 16, 0, 0); \
    } \
  } while (0)

template <int MODE>
__global__ __launch_bounds__(512, 2) void gemm8(
    const _Float16* __restrict__ A0, const _Float16* __restrict__ B0,
    const _Float16* __restrict__ A1, const _Float16* __restrict__ B1,
    const _Float16* __restrict__ A2, const _Float16* __restrict__ B2,
    int N, int Kp, float* __restrict__ Cf, _Float16* __restrict__ GP)
{
    __shared__ __align__(128) char Lc[131072];   // 2 bufs x (A 32K + B 32K)
    const int tid  = threadIdx.x;
    const int lane = tid & 63;
    const int wave = tid >> 6;
    const int wr = wave >> 2, wc = wave & 3;     // 2 x 4 waves

    // XCD-bijective swizzle of flattened block id
    const int gx = gridDim.x, gy = gridDim.y;
    const int nwg = gx * gy;
    const int orig = blockIdx.y * gx + blockIdx.x;
    const int q = nwg >> 3, r = nwg & 7, xcd = orig & 7, lid = orig >> 3;
    const int wg = (xcd < r ? xcd * (q + 1) : r * (q + 1) + (xcd - r) * q) + lid;
    const int bm = wg / gy, bn = wg % gy;

    // staging map: linear LDS dest <- inverse-swizzled global source
    const int p0 = tid * 16, p1 = p0 + 8192;
    const int l0 = swz(p0), l1 = swz(p1);
    const int srow0 = l0 >> 7, scol0 = (l0 & 127) >> 1;
    const int srow1 = l1 >> 7, scol1 = (l1 & 127) >> 1;
    char* ldsw = Lc + wave * 1024;

    // swizzled ds_read bases: row&7 == lane&7 -> constant XOR; k toggles bit 6
    const int l15 = lane & 15, lhi = lane >> 4, ax = (lane & 7) << 4;
    const int aof0 = (wr * 8192 + l15 * 128 + lhi * 16) ^ ax;
    const int aof1 = aof0 ^ 64;
    const int bof0 = (wc * 4096 + l15 * 128 + lhi * 16) ^ ax;
    const int bof1 = bof0 ^ 64;

    const int tpp = Kp >> 6;                      // K-tiles per pass (>=32)
    const int NT  = (MODE == 2 ? 3 : 1) * tpp;

    f32x4 acc[8][4] = {};
    f16x8 a0f[4][2], a1f[4][2], bf[2][2];

    // prologue: stage all 4 halves of tile0 -> buf0, drain, collect
    STAGE(true, A0, B0, 0, 0, 0, 0);
    STAGE(true, A0, B0, 0, 1, 0, 0);
    STAGE(true, A0, B0, 0, 0, 1, 0);
    STAGE(true, A0, B0, 0, 1, 1, 0);
    asm volatile("s_waitcnt vmcnt(0)" ::: "memory");
    BARR;

    for (int t = 0; t < NT; ++t) {
        const int buf = t & 1, bufn = buf ^ 1;
        if (MODE == 2 && t == 2 * tpp) {
            #pragma unroll
            for (int m = 0; m < 8; ++m)
                #pragma unroll
                for (int n = 0; n < 4; ++n)
                    acc[m][n] *= (1.0f / 2048.0f);
        }
        const int ts1 = t + 1;
        const bool ok1 = ts1 < NT;
        const _Float16 *pA1 = A0, *pB1 = B0;
        int kt1 = 0;
        if (MODE == 2) {
            if (ok1) { int ps = ts1 / tpp; kt1 = (ts1 - ps * tpp) << 6;
                       pA1 = ps == 0 ? A0 : (ps == 1 ? A1 : A2);
                       pB1 = ps == 0 ? B0 : (ps == 1 ? B1 : B2); }
        } else { kt1 = ts1 << 6; }

        // ph0: reads a0f(Ah0), bf(Bh0) [12]; stage Ah0(t+1); barrier; lgkm0; q(m0,n0)
        RD_A(a0f, 0, buf);
        RD_B(bf, 0, buf);
        STAGE(ok1, pA1, pB1, kt1, 0, 0, bufn);
        SYNC_MFMA;
        QUADM(a0f, bf, 0, 0);
        BARR;

        // ph1: reads a1f(Ah1) [8]; stage Bh0(t+1); gate vmcnt(4) [covers Bh1(t)]
        RD_A(a1f, 1, buf);
        STAGE(ok1, pA1, pB1, kt1, 1, 0, bufn);
        if (ok1) asm volatile("s_waitcnt vmcnt(4)" ::: "memory");
        else     asm volatile("s_waitcnt vmcnt(0)" ::: "memory");
        SYNC_MFMA;
        QUADM(a1f, bf, 1, 0);
        BARR;

        // ph2: reads bf(Bh1) [4]; stage Ah1(t+1); barrier; lgkm0; q(m1,n1)
        RD_B(bf, 1, buf);
        STAGE(ok1, pA1, pB1, kt1, 0, 1, bufn);
        SYNC_MFMA;
        QUADM(a1f, bf, 1, 1);
        BARR;

        // ph3: no reads; stage Bh1(t+1); gate vmcnt(2) [covers Ah0,Bh0,Ah1(t+1)]
        STAGE(ok1, pA1, pB1, kt1, 1, 1, bufn);
        if (ok1) asm volatile("s_waitcnt vmcnt(2)" ::: "memory");
        else     asm volatile("s_waitcnt vmcnt(0)" ::: "memory");
        BARR;
        QUADM(a0f, bf, 0, 1);
        BARR;
    }

    // epilogue; C/D layout: col = lane&15, row = (lane>>4)*4 + reg
    const int r0 = bm * 256 + wr * 64 + (lane >> 4) * 4;
    const int c0 = bn * 256 + wc * 32 + (lane & 15);
    #pragma unroll
    for (int mf = 0; mf < 8; ++mf) {
        const int row = r0 + (mf >> 2) * 128 + (mf & 3) * 16;
        #pragma unroll
        for (int nf = 0; nf < 4; ++nf) {
            const int col = c0 + (nf >> 1) * 128 + (nf & 1) * 16;
            #pragma unroll
            for (int rr = 0; rr < 4; ++rr) {
                const size_t idx = (size_t)(row + rr) * N + col;
                if (MODE == 1) {
                    float g = (float)GP[idx];
                    GP[idx] = (_Float16)(g * acc[mf][nf][rr]);
                } else {
                    Cf[idx] = acc[mf][nf][rr];
                }
            }
        }
    }
}

// ---------------- exact K-th largest |gate| per token + fused mask write ----------------

__global__ __launch_bounds__(256) void topk_mask(const float* __restrict__ gate,
                                                 _Float16* __restrict__ gm) {
    __shared__ unsigned keys[IDIM];
    __shared__ unsigned hist[256];
    __shared__ unsigned sA[256], sB[256];
    __shared__ unsigned selBin, selAbove;

    const int tid = threadIdx.x;
    const int t = blockIdx.x;
    const float* row = gate + (size_t)t * IDIM;

    for (int j = tid; j < IDIM; j += 256)
        keys[j] = __float_as_uint(fabsf(row[j]));
    __syncthreads();

    unsigned prefix = 0;
    int Krem = KKEEP;
    for (int pass = 0; pass < 4; ++pass) {
        const int shift = 24 - 8 * pass;
        hist[tid] = 0;
        __syncthreads();
        for (int j = tid; j < IDIM; j += 256) {
            unsigned k = keys[j];
            bool ok = (pass == 0) || (((k ^ prefix) >> (shift + 8)) == 0u);
            if (ok) atomicAdd(&hist[(k >> shift) & 255u], 1u);
        }
        __syncthreads();
        sA[tid] = hist[tid];
        __syncthreads();
        unsigned* src = sA; unsigned* dst = sB;
        for (int off = 1; off < 256; off <<= 1) {
            unsigned v = src[tid] + ((tid + off < 256) ? src[tid + off] : 0u);
            dst[tid] = v;
            __syncthreads();
            unsigned* tmp = src; src = dst; dst = tmp;
        }
        unsigned S  = src[tid];
        unsigned Sn = (tid < 255) ? src[tid + 1] : 0u;
        if ((int)S >= Krem && (int)Sn < Krem) { selBin = (unsigned)tid; selAbove = Sn; }
        __syncthreads();
        prefix |= (selBin << shift);
        Krem -= (int)selAbove;
        __syncthreads();
    }
    const float kthv = __uint_as_float(prefix);
    _Float16* g16 = gm + (size_t)t * IDIM;
    for (int j = tid; j < IDIM; j += 256) {
        float g = row[j];
        g16[j] = (fabsf(g) >= kthv) ? (_Float16)g : (_Float16)0.0f;
    }
}

// ---------------- host ----------------

extern "C" void kernel_launch(void* const* d_in, const int* in_sizes, int n_in,
                              void* d_out, int out_size, void* d_ws, size_t ws_size,
                              hipStream_t stream) {
    const float* x  = (const float*)d_in[0];   // [T,H]
    const float* Wg = (const float*)d_in[1];   // [I,H]
    const float* Wu = (const float*)d_in[2];   // [I,H]
    const float* Wd = (const float*)d_in[3];   // [H,I]

    const size_t NE   = (size_t)T_TOK * HDIM;
    const size_t szH2 = NE * 2;                          // 33.55 MB

    char* ws = (char*)d_ws;
    _Float16* xh    = (_Float16*)ws;
    _Float16* Wb    = (_Float16*)(ws + szH2);            // Wgh, later Wu16
    _Float16* Wc    = (_Float16*)(ws + 2 * szH2);        // Wgl2, later Wd16
    _Float16* gmask = (_Float16*)(ws + 3 * szH2);        // masked gate f16 -> P (in place)
    _Float16* xl2   = gmask + (size_t)6144 * IDIM;       // parked; consumed before overwritten
    float* gate = (float*)d_out;                         // 2048-token f32 gate chunk

    const long n4 = (long)(NE / 4);
    cast_split<<<1024, 256, 0, stream>>>((const float4*)x,  (ushort4*)xh, (ushort4*)xl2, n4);
    cast_split<<<1024, 256, 0, stream>>>((const float4*)Wg, (ushort4*)Wb, (ushort4*)Wc,  n4);

    // gate phase: fused 3-pass split-f16 GEMM:
    // acc = xl2@Wgh + xh@Wgl2; acc *= 2^-11; acc += xh@Wgh
    for (int c0 = 0; c0 < T_TOK; c0 += 2048) {
        const _Float16* xh_c  = xh  + (size_t)c0 * HDIM;
        const _Float16* xl2_c = xl2 + (size_t)c0 * HDIM;
        gemm8<2><<<dim3(2048 / 256, IDIM / 256), 512, 0, stream>>>(
            xl2_c, Wb, xh_c, Wc, xh_c, Wb, IDIM, HDIM, gate, nullptr);
        topk_mask<<<2048, 256, 0, stream>>>(gate, gmask + (size_t)c0 * IDIM);
    }

    // re-cast weight slots for UP / DOWN
    cast_f16<<<1024, 256, 0, stream>>>((const float4*)Wu, (ushort4*)Wb, n4);
    cast_f16<<<1024, 256, 0, stream>>>((const float4*)Wd, (ushort4*)Wc, n4);

    // UP: in-place P = gmask * (xh @ Wu^T)
    gemm8<1><<<dim3(T_TOK / 256, IDIM / 256), 512, 0, stream>>>(
        xh, Wb, nullptr, nullptr, nullptr, nullptr, IDIM, HDIM, nullptr, gmask);

    // DOWN: out = P @ Wd^T
    gemm8<0><<<dim3(T_TOK / 256, HDIM / 256), 512, 0, stream>>>(
        (const _Float16*)gmask, Wc, nullptr, nullptr, nullptr, nullptr,
        HDIM, IDIM, (float*)d_out, nullptr);
}

// Round 9
// 1831.281 us; speedup vs baseline: 1.0259x; 1.0259x over previous
//
#include <hip/hip_runtime.h>

#define T_TOK 8192   // B*S tokens
#define HDIM  2048
#define IDIM  8192
#define KKEEP 4096

typedef _Float16 f16x8 __attribute__((ext_vector_type(8)));
typedef float    f32x4 __attribute__((ext_vector_type(4)));

#define AS1 __attribute__((address_space(1)))
#define AS3 __attribute__((address_space(3)))

// LDS swizzle within a 16KB half-tile (128 rows x 128B): byte ^= (row&7)<<4.
__device__ __forceinline__ int swz(int b) { return b ^ (((b >> 7) & 7) << 4); }

#define BARR asm volatile("s_barrier" ::: "memory")
// K-tile boundary: drain own ds_reads (WAR) + own staging loads (RAW), then collect.
#define TILE_SYNC do { \
    asm volatile("s_waitcnt lgkmcnt(0)" ::: "memory"); \
    asm volatile("s_waitcnt vmcnt(0)" ::: "memory"); \
    BARR; } while (0)

// ---------------- cast kernels ----------------

__global__ void cast_split(const float4* __restrict__ in, ushort4* __restrict__ hi,
                           ushort4* __restrict__ lo2, long n4) {
    long stride = (long)gridDim.x * blockDim.x;
    for (long i = (long)blockIdx.x * blockDim.x + threadIdx.x; i < n4; i += stride) {
        float4 v = in[i];
        float vv[4] = {v.x, v.y, v.z, v.w};
        union { _Float16 f[4]; ushort4 u; } H, L;
        #pragma unroll
        for (int j = 0; j < 4; ++j) {
            _Float16 h = (_Float16)vv[j];
            H.f[j] = h;
            L.f[j] = (_Float16)((vv[j] - (float)h) * 2048.0f);
        }
        hi[i] = H.u;
        lo2[i] = L.u;
    }
}

__global__ void cast_f16(const float4* __restrict__ in, ushort4* __restrict__ o, long n4) {
    long stride = (long)gridDim.x * blockDim.x;
    for (long i = (long)blockIdx.x * blockDim.x + threadIdx.x; i < n4; i += stride) {
        float4 v = in[i];
        float vv[4] = {v.x, v.y, v.z, v.w};
        union { _Float16 f[4]; ushort4 u; } H;
        #pragma unroll
        for (int j = 0; j < 4; ++j) H.f[j] = (_Float16)vv[j];
        o[i] = H.u;
    }
}

// ---------------- 256x256 GEMM, 1 barrier per K-tile, compiler-scheduled body ----
// MODE 0: DOWN — Cf = A0@B0^T (f32)
// MODE 1: UP   — in-place GP[idx] = (f16)((float)GP[idx] * acc)
// MODE 2: GATE — acc = A0@B0^T + A1@B1^T; acc *= 2^-11; acc += A2@B2^T; Cf f32

#define RD_A(dst_, mh_, buf_) do { \
    const char* b_ = Lc + (buf_)*65536 + (mh_)*16384; \
    _Pragma("unroll") \
    for (int f_ = 0; f_ < 4; ++f_) { \
      (dst_)[f_][0] = *(const f16x8*)(b_ + aof0 + f_*2048); \
      (dst_)[f_][1] = *(const f16x8*)(b_ + aof1 + f_*2048); \
    } \
  } while (0)

#define RD_B(dst_, nh_, buf_) do { \
    const char* b_ = Lc + (buf_)*65536 + 32768 + (nh_)*16384; \
    _Pragma("unroll") \
    for (int n_ = 0; n_ < 2; ++n_) { \
      (dst_)[n_][0] = *(const f16x8*)(b_ + bof0 + n_*2048); \
      (dst_)[n_][1] = *(const f16x8*)(b_ + bof1 + n_*2048); \
    } \
  } while (0)

#define QUADM(af_, bf_, mh_, nh_) do { \
    __builtin_amdgcn_s_setprio(1); \
    _Pragma("unroll") \
    for (int f_ = 0; f_ < 4; ++f_) { \
      _Pragma("unroll") \
      for (int n_ = 0; n_ < 2; ++n_) { \
        _Pragma("unroll") \
        for (int k_ = 0; k_ < 2; ++k_) \
          acc[(mh_)*4+f_][(nh_)*2+n_] = __builtin_amdgcn_mfma_f32_16x16x32_f16( \
              (af_)[f_][k_], (bf_)[n_][k_], acc[(mh_)*4+f_][(nh_)*2+n_], 0, 0, 0); \
      } \
    } \
    __builtin_amdgcn_s_setprio(0); \
  } while (0)

// stage one half-tile: mat_ 0=A 1=B, h_ half, buf_ target buffer
#define STAGE(ok_, pA_, pB_, kt_, mat_, h_, buf_) do { \
    if (ok_) { \
      const _Float16* mb_ = (mat_) == 0 ? (pA_) : (pB_); \
      const int rb_ = ((mat_) == 0 ? bm : bn) * 256 + (h_)*128; \
      char* ld_ = ldsw + (buf_)*65536 + (mat_)*32768 + (h_)*16384; \
      __builtin_amdgcn_global_load_lds((const AS1 void*)(mb_ + (size_t)(rb_ + srow0)*Kp + (kt_) + scol0), \
                                       (AS3 void*)ld_, 16, 0, 0); \
      __builtin_amdgcn_global_load_lds((const AS1 void*)(mb_ + (size_t)(rb_ + srow1)*Kp + (kt_) + scol1), \
                                       (AS3 void*)(ld_ + 8192), 16, 0, 0); \
    } \
  } while (0)

template <int MODE>
__global__ __launch_bounds__(512, 2) void gemm8(
    const _Float16* __restrict__ A0, const _Float16* __restrict__ B0,
    const _Float16* __restrict__ A1, const _Float16* __restrict__ B1,
    const _Float16* __restrict__ A2, const _Float16* __restrict__ B2,
    int N, int Kp, float* __restrict__ Cf, _Float16* __restrict__ GP)
{
    __shared__ __align__(128) char Lc[131072];   // 2 bufs x (A 32K + B 32K)
    const int tid  = threadIdx.x;
    const int lane = tid & 63;
    const int wave = tid >> 6;
    const int wr = wave >> 2, wc = wave & 3;     // 2 x 4 waves

    // XCD-bijective swizzle of flattened block id
    const int gx = gridDim.x, gy = gridDim.y;
    const int nwg = gx * gy;
    const int orig = blockIdx.y * gx + blockIdx.x;
    const int q = nwg >> 3, r = nwg & 7, xcd = orig & 7, lid = orig >> 3;
    const int wg = (xcd < r ? xcd * (q + 1) : r * (q + 1) + (xcd - r) * q) + lid;
    const int bm = wg / gy, bn = wg % gy;

    // staging map: linear LDS dest <- inverse-swizzled global source
    const int p0 = tid * 16, p1 = p0 + 8192;
    const int l0 = swz(p0), l1 = swz(p1);
    const int srow0 = l0 >> 7, scol0 = (l0 & 127) >> 1;
    const int srow1 = l1 >> 7, scol1 = (l1 & 127) >> 1;
    char* ldsw = Lc + wave * 1024;

    // swizzled ds_read bases: row&7 == lane&7 -> constant XOR; k toggles bit 6
    const int l15 = lane & 15, lhi = lane >> 4, ax = (lane & 7) << 4;
    const int aof0 = (wr * 8192 + l15 * 128 + lhi * 16) ^ ax;
    const int aof1 = aof0 ^ 64;
    const int bof0 = (wc * 4096 + l15 * 128 + lhi * 16) ^ ax;
    const int bof1 = bof0 ^ 64;

    const int tpp = Kp >> 6;                      // K-tiles per pass (>=32)
    const int NT  = (MODE == 2 ? 3 : 1) * tpp;

    f32x4 acc[8][4] = {};
    f16x8 a0f[4][2], a1f[4][2], b0f[2][2], b1f[2][2];

    // prologue: stage all 4 halves of tile0 -> buf0
    STAGE(true, A0, B0, 0, 0, 0, 0);
    STAGE(true, A0, B0, 0, 1, 0, 0);
    STAGE(true, A0, B0, 0, 0, 1, 0);
    STAGE(true, A0, B0, 0, 1, 1, 0);

    for (int t = 0; t < NT; ++t) {
        const int buf = t & 1, bufn = buf ^ 1;

        // K-tile boundary: tile t's stages landed (RAW), own reads of bufn drained (WAR)
        TILE_SYNC;

        if (MODE == 2 && t == 2 * tpp) {
            #pragma unroll
            for (int m = 0; m < 8; ++m)
                #pragma unroll
                for (int n = 0; n < 4; ++n)
                    acc[m][n] *= (1.0f / 2048.0f);
        }

        // resolve + issue next tile's staging immediately (full K-tile of lead)
        const int ts1 = t + 1;
        const bool ok1 = ts1 < NT;
        const _Float16 *pA1 = A0, *pB1 = B0;
        int kt1 = 0;
        if (MODE == 2) {
            if (ok1) { int ps = ts1 / tpp; kt1 = (ts1 - ps * tpp) << 6;
                       pA1 = ps == 0 ? A0 : (ps == 1 ? A1 : A2);
                       pB1 = ps == 0 ? B0 : (ps == 1 ? B1 : B2); }
        } else { kt1 = ts1 << 6; }
        STAGE(ok1, pA1, pB1, kt1, 0, 0, bufn);
        STAGE(ok1, pA1, pB1, kt1, 1, 0, bufn);
        STAGE(ok1, pA1, pB1, kt1, 0, 1, bufn);
        STAGE(ok1, pA1, pB1, kt1, 1, 1, bufn);

        // whole-tile body: 24 ds_reads + 64 MFMA, compiler-scheduled interleave
        RD_A(a0f, 0, buf);
        RD_B(b0f, 0, buf);
        QUADM(a0f, b0f, 0, 0);
        RD_A(a1f, 1, buf);
        QUADM(a1f, b0f, 1, 0);
        RD_B(b1f, 1, buf);
        QUADM(a1f, b1f, 1, 1);
        QUADM(a0f, b1f, 0, 1);
    }

    // epilogue; C/D layout: col = lane&15, row = (lane>>4)*4 + reg
    const int r0 = bm * 256 + wr * 64 + (lane >> 4) * 4;
    const int c0 = bn * 256 + wc * 32 + (lane & 15);
    #pragma unroll
    for (int mf = 0; mf < 8; ++mf) {
        const int row = r0 + (mf >> 2) * 128 + (mf & 3) * 16;
        #pragma unroll
        for (int nf = 0; nf < 4; ++nf) {
            const int col = c0 + (nf >> 1) * 128 + (nf & 1) * 16;
            #pragma unroll
            for (int rr = 0; rr < 4; ++rr) {
                const size_t idx = (size_t)(row + rr) * N + col;
                if (MODE == 1) {
                    float g = (float)GP[idx];
                    GP[idx] = (_Float16)(g * acc[mf][nf][rr]);
                } else {
                    Cf[idx] = acc[mf][nf][rr];
                }
            }
        }
    }
}

// ---------------- exact K-th largest |gate| per token + fused mask write ----------------

__global__ __launch_bounds__(256) void topk_mask(const float* __restrict__ gate,
                                                 _Float16* __restrict__ gm) {
    __shared__ unsigned keys[IDIM];
    __shared__ unsigned hist[256];
    __shared__ unsigned sA[256], sB[256];
    __shared__ unsigned selBin, selAbove;

    const int tid = threadIdx.x;
    const int t = blockIdx.x;
    const float* row = gate + (size_t)t * IDIM;

    for (int j = tid; j < IDIM; j += 256)
        keys[j] = __float_as_uint(fabsf(row[j]));
    __syncthreads();

    unsigned prefix = 0;
    int Krem = KKEEP;
    for (int pass = 0; pass < 4; ++pass) {
        const int shift = 24 - 8 * pass;
        hist[tid] = 0;
        __syncthreads();
        for (int j = tid; j < IDIM; j += 256) {
            unsigned k = keys[j];
            bool ok = (pass == 0) || (((k ^ prefix) >> (shift + 8)) == 0u);
            if (ok) atomicAdd(&hist[(k >> shift) & 255u], 1u);
        }
        __syncthreads();
        sA[tid] = hist[tid];
        __syncthreads();
        unsigned* src = sA; unsigned* dst = sB;
        for (int off = 1; off < 256; off <<= 1) {
            unsigned v = src[tid] + ((tid + off < 256) ? src[tid + off] : 0u);
            dst[tid] = v;
            __syncthreads();
            unsigned* tmp = src; src = dst; dst = tmp;
        }
        unsigned S  = src[tid];
        unsigned Sn = (tid < 255) ? src[tid + 1] : 0u;
        if ((int)S >= Krem && (int)Sn < Krem) { selBin = (unsigned)tid; selAbove = Sn; }
        __syncthreads();
        prefix |= (selBin << shift);
        Krem -= (int)selAbove;
        __syncthreads();
    }
    const float kthv = __uint_as_float(prefix);
    _Float16* g16 = gm + (size_t)t * IDIM;
    for (int j = tid; j < IDIM; j += 256) {
        float g = row[j];
        g16[j] = (fabsf(g) >= kthv) ? (_Float16)g : (_Float16)0.0f;
    }
}

// ---------------- host ----------------

extern "C" void kernel_launch(void* const* d_in, const int* in_sizes, int n_in,
                              void* d_out, int out_size, void* d_ws, size_t ws_size,
                              hipStream_t stream) {
    const float* x  = (const float*)d_in[0];   // [T,H]
    const float* Wg = (const float*)d_in[1];   // [I,H]
    const float* Wu = (const float*)d_in[2];   // [I,H]
    const float* Wd = (const float*)d_in[3];   // [H,I]

    const size_t NE   = (size_t)T_TOK * HDIM;
    const size_t szH2 = NE * 2;                          // 33.55 MB

    char* ws = (char*)d_ws;
    _Float16* xh    = (_Float16*)ws;
    _Float16* Wb    = (_Float16*)(ws + szH2);            // Wgh, later Wu16
    _Float16* Wc    = (_Float16*)(ws + 2 * szH2);        // Wgl2, later Wd16
    _Float16* gmask = (_Float16*)(ws + 3 * szH2);        // masked gate f16 -> P (in place)
    _Float16* xl2   = gmask + (size_t)6144 * IDIM;       // parked; consumed before overwritten
    float* gate = (float*)d_out;                         // 2048-token f32 gate chunk

    const long n4 = (long)(NE / 4);
    cast_split<<<1024, 256, 0, stream>>>((const float4*)x,  (ushort4*)xh, (ushort4*)xl2, n4);
    cast_split<<<1024, 256, 0, stream>>>((const float4*)Wg, (ushort4*)Wb, (ushort4*)Wc,  n4);

    // gate phase: fused 3-pass split-f16 GEMM:
    // acc = xl2@Wgh + xh@Wgl2; acc *= 2^-11; acc += xh@Wgh
    for (int c0 = 0; c0 < T_TOK; c0 += 2048) {
        const _Float16* xh_c  = xh  + (size_t)c0 * HDIM;
        const _Float16* xl2_c = xl2 + (size_t)c0 * HDIM;
        gemm8<2><<<dim3(2048 / 256, IDIM / 256), 512, 0, stream>>>(
            xl2_c, Wb, xh_c, Wc, xh_c, Wb, IDIM, HDIM, gate, nullptr);
        topk_mask<<<2048, 256, 0, stream>>>(gate, gmask + (size_t)c0 * IDIM);
    }

    // re-cast weight slots for UP / DOWN
    cast_f16<<<1024, 256, 0, stream>>>((const float4*)Wu, (ushort4*)Wb, n4);
    cast_f16<<<1024, 256, 0, stream>>>((const float4*)Wd, (ushort4*)Wc, n4);

    // UP: in-place P = gmask * (xh @ Wu^T)
    gemm8<1><<<dim3(T_TOK / 256, IDIM / 256), 512, 0, stream>>>(
        xh, Wb, nullptr, nullptr, nullptr, nullptr, IDIM, HDIM, nullptr, gmask);

    // DOWN: out = P @ Wd^T
    gemm8<0><<<dim3(T_TOK / 256, HDIM / 256), 512, 0, stream>>>(
        (const _Float16*)gmask, Wc, nullptr, nullptr, nullptr, nullptr,
        HDIM, IDIM, (float*)d_out, nullptr);
}